// Round 1
// baseline (12683.414 us; speedup 1.0000x reference)
//
#include <hip/hip_runtime.h>
#include <hip/hip_bf16.h>

#define BATCH 128

// ---------------- decode: x[b, p0[i]] = y[b,i] / s0[i], drop homogeneous ----------------
__global__ void decode_kernel(const float* __restrict__ y, const int* __restrict__ p,
                              const float* __restrict__ s, float* __restrict__ x) {
    const int n = 3073;
    int idx = blockIdx.x * blockDim.x + threadIdx.x;
    if (idx >= BATCH * n) return;
    int i = idx % n, b = idx / n;
    int pi = p[i];
    float v = y[(size_t)b * n + i] / s[i];
    if (pi < 3072) x[(size_t)b * 3072 + pi] = v;
}

// ---------------- direct 3x3 conv, pad=1, fused bias+relu ----------------
template <int CIN, int HIN, int WIN, int STRIDE>
__global__ void conv3x3_kernel(const float* __restrict__ in, const float* __restrict__ wt,
                               const float* __restrict__ bias, float* __restrict__ out,
                               int Cout) {
    constexpr int HOUT = HIN / STRIDE;
    constexpr int WOUT = WIN / STRIDE;
    int idx = blockIdx.x * blockDim.x + threadIdx.x;
    int total = BATCH * Cout * HOUT * WOUT;
    if (idx >= total) return;
    int ow = idx % WOUT; int t = idx / WOUT;
    int oh = t % HOUT;   t /= HOUT;
    int co = t % Cout;   int b = t / Cout;

    const float* inb = in + (size_t)b * CIN * HIN * WIN;
    const float* wco = wt + (size_t)co * CIN * 9;
    int ih0 = oh * STRIDE - 1;
    int iw0 = ow * STRIDE - 1;

    float acc = bias[co];
    for (int ci = 0; ci < CIN; ++ci) {
        const float* ip = inb + ci * HIN * WIN;
        const float* wp = wco + ci * 9;
#pragma unroll
        for (int kh = 0; kh < 3; ++kh) {
            int ih = ih0 + kh;
            if (ih < 0 || ih >= HIN) continue;
#pragma unroll
            for (int kw = 0; kw < 3; ++kw) {
                int iw = iw0 + kw;
                if (iw < 0 || iw >= WIN) continue;
                acc = fmaf(ip[ih * WIN + iw], wp[kh * 3 + kw], acc);
            }
        }
    }
    out[idx] = fmaxf(acc, 0.0f);
}

// ---------------- 1x1 conv, fused bias (+optional relu) ----------------
__global__ void conv1x1_kernel(const float* __restrict__ in, const float* __restrict__ wt,
                               const float* __restrict__ bias, float* __restrict__ out,
                               int Cin, int Cout, int HW, int relu) {
    int idx = blockIdx.x * blockDim.x + threadIdx.x;
    int total = BATCH * Cout * HW;
    if (idx >= total) return;
    int p = idx % HW; int t = idx / HW;
    int co = t % Cout; int b = t / Cout;
    const float* inb = in + (size_t)b * Cin * HW;
    const float* wco = wt + (size_t)co * Cin;
    float acc = bias[co];
    for (int ci = 0; ci < Cin; ++ci)
        acc = fmaf(inb[ci * HW + p], wco[ci], acc);
    out[idx] = relu ? fmaxf(acc, 0.0f) : acc;
}

// ---------------- fully-connected: out[b,o] = relu?(x[b,:] . W[o,:] + b[o]) ----------------
__global__ void fc_kernel(const float* __restrict__ in, const float* __restrict__ wt,
                          const float* __restrict__ bias, float* __restrict__ out,
                          int IN, int OUT, int relu) {
    int idx = blockIdx.x * blockDim.x + threadIdx.x;
    if (idx >= BATCH * OUT) return;
    int o = idx % OUT, b = idx / OUT;
    const float* inb = in + (size_t)b * IN;
    const float* wo  = wt + (size_t)o * IN;
    float acc = bias[o];
    for (int i = 0; i < IN; ++i)
        acc = fmaf(inb[i], wo[i], acc);
    out[idx] = relu ? fmaxf(acc, 0.0f) : acc;
}

// ---------------- final encode: out[b,i] = s11[i] * (p11[i]==10 ? 1 : logits[b,p11[i]]) ----
__global__ void encode_kernel(const float* __restrict__ logits, const int* __restrict__ p,
                              const float* __restrict__ s, float* __restrict__ out) {
    int idx = blockIdx.x * blockDim.x + threadIdx.x;
    if (idx >= BATCH * 11) return;
    int i = idx % 11, b = idx / 11;
    int pi = p[i];
    float v = (pi == 10) ? 1.0f : logits[(size_t)b * 10 + pi];
    out[idx] = s[i] * v;
}

extern "C" void kernel_launch(void* const* d_in, const int* in_sizes, int n_in,
                              void* d_out, int out_size, void* d_ws, size_t ws_size,
                              hipStream_t stream) {
    // Input indices per setup_inputs() dict order
    const int*   p0  = (const int*)  d_in[0];
    const float* s0  = (const float*)d_in[1];
    const int*   p11 = (const int*)  d_in[26];
    const float* s11 = (const float*)d_in[27];
    const float* w1 = (const float*)d_in[28]; const float* b1 = (const float*)d_in[29];
    const float* w2 = (const float*)d_in[30]; const float* b2 = (const float*)d_in[31];
    const float* w3 = (const float*)d_in[32]; const float* b3 = (const float*)d_in[33];
    const float* w4 = (const float*)d_in[34]; const float* b4 = (const float*)d_in[35];
    const float* w5 = (const float*)d_in[36]; const float* b5 = (const float*)d_in[37];
    const float* w6 = (const float*)d_in[38]; const float* b6 = (const float*)d_in[39];
    const float* w7 = (const float*)d_in[40]; const float* b7 = (const float*)d_in[41];
    const float* w8 = (const float*)d_in[42]; const float* b8 = (const float*)d_in[43];
    const float* w9 = (const float*)d_in[44]; const float* b9 = (const float*)d_in[45];
    const float* fw1 = (const float*)d_in[46]; const float* fb1 = (const float*)d_in[47];
    const float* fw2 = (const float*)d_in[48]; const float* fb2 = (const float*)d_in[49];
    const float* A0 = (const float*)d_in[50];
    float* out = (float*)d_out;

    // ping-pong activation buffers (48 MB each)
    float* bufA = (float*)d_ws;
    float* bufB = bufA + (size_t)12582912;  // 128*96*32*32

    const int TPB = 256;
    auto blocks = [](int total, int tpb) { return (total + tpb - 1) / tpb; };

    // decode input -> bufA (128,3,32,32)
    decode_kernel<<<blocks(BATCH * 3073, TPB), TPB, 0, stream>>>(A0, p0, s0, bufA);

    // conv1: 3->96 @32x32
    conv3x3_kernel<3, 32, 32, 1><<<blocks(BATCH * 96 * 1024, TPB), TPB, 0, stream>>>(
        bufA, w1, b1, bufB, 96);
    // conv2: 96->96 @32x32
    conv3x3_kernel<96, 32, 32, 1><<<blocks(BATCH * 96 * 1024, TPB), TPB, 0, stream>>>(
        bufB, w2, b2, bufA, 96);
    // conv3: 96->96 @32x32 stride2 -> 16x16
    conv3x3_kernel<96, 32, 32, 2><<<blocks(BATCH * 96 * 256, TPB), TPB, 0, stream>>>(
        bufA, w3, b3, bufB, 96);
    // conv4: 96->192 @16x16
    conv3x3_kernel<96, 16, 16, 1><<<blocks(BATCH * 192 * 256, TPB), TPB, 0, stream>>>(
        bufB, w4, b4, bufA, 192);
    // conv5: 192->192 @16x16
    conv3x3_kernel<192, 16, 16, 1><<<blocks(BATCH * 192 * 256, TPB), TPB, 0, stream>>>(
        bufA, w5, b5, bufB, 192);
    // conv6: 192->192 @16x16 stride2 -> 8x8
    conv3x3_kernel<192, 16, 16, 2><<<blocks(BATCH * 192 * 64, TPB), TPB, 0, stream>>>(
        bufB, w6, b6, bufA, 192);
    // conv7: 192->192 @8x8
    conv3x3_kernel<192, 8, 8, 1><<<blocks(BATCH * 192 * 64, TPB), TPB, 0, stream>>>(
        bufA, w7, b7, bufB, 192);
    // conv8: 1x1 192->192 @8x8
    conv1x1_kernel<<<blocks(BATCH * 192 * 64, TPB), TPB, 0, stream>>>(
        bufB, w8, b8, bufA, 192, 192, 64, 1);
    // conv9: 1x1 192->10 @8x8
    conv1x1_kernel<<<blocks(BATCH * 10 * 64, TPB), TPB, 0, stream>>>(
        bufA, w9, b9, bufB, 192, 10, 64, 1);
    // fc1: 640->100 + relu
    fc_kernel<<<blocks(BATCH * 100, TPB), TPB, 0, stream>>>(bufB, fw1, fb1, bufA, 640, 100, 1);
    // fc2: 100->10
    fc_kernel<<<blocks(BATCH * 10, TPB), TPB, 0, stream>>>(bufA, fw2, fb2, bufB, 100, 10, 0);
    // encode -> d_out (128,11)
    encode_kernel<<<blocks(BATCH * 11, TPB), TPB, 0, stream>>>(bufB, p11, s11, out);
}

// Round 2
// 780.340 us; speedup vs baseline: 16.2537x; 16.2537x over previous
//
#include <hip/hip_runtime.h>
#include <hip/hip_bf16.h>

#define BATCH 128
#define CDIV(a, b) (((a) + (b) - 1) / (b))

typedef __attribute__((ext_vector_type(8))) short short8;
typedef __attribute__((ext_vector_type(4))) float f32x4;

// ---------------- zero fill (f32) ----------------
__global__ void fill0_f32(float* __restrict__ p, int n) {
    int i = blockIdx.x * blockDim.x + threadIdx.x;
    if (i < n) p[i] = 0.0f;
}

// ---------------- decode: scatter A0 -> padded NHWC f32 [B][34][34][4] ----------------
__global__ void decode_kernel(const float* __restrict__ y, const int* __restrict__ p,
                              const float* __restrict__ s, float* __restrict__ x) {
    const int n = 3073;
    int idx = blockIdx.x * blockDim.x + threadIdx.x;
    if (idx >= BATCH * n) return;
    int i = idx % n, b = idx / n;
    int pi = p[i];
    if (pi >= 3072) return;
    float v = y[(size_t)b * n + i] / s[i];
    int c = pi >> 10; int r = pi & 1023; int h = r >> 5; int w = r & 31;
    x[((size_t)(b * 34 + h + 1) * 34 + (w + 1)) * 4 + c] = v;
}

// ---------------- halo zero for bf16 NHWC padded buffer ----------------
__global__ void halo_zero(__hip_bfloat16* __restrict__ buf, int Hp, int Wp, int C) {
    int haloPix = 2 * Wp + 2 * (Hp - 2);
    int total = BATCH * haloPix * C;
    int idx = blockIdx.x * blockDim.x + threadIdx.x;
    if (idx >= total) return;
    int c = idx % C; int t = idx / C; int hp = t % haloPix; int b = t / haloPix;
    int h, w;
    if (hp < Wp)            { h = 0;        w = hp; }
    else if (hp < 2 * Wp)   { h = Hp - 1;   w = hp - Wp; }
    else { int r = hp - 2 * Wp; h = 1 + (r >> 1); w = (r & 1) ? (Wp - 1) : 0; }
    buf[((size_t)(b * Hp + h) * Wp + w) * C + c] = __float2bfloat16(0.0f);
}

// ---------------- weight transform: OIHW f32 -> [KK][CoutPad][Cin] bf16 ----------------
__global__ void wt_transform(const float* __restrict__ w, __hip_bfloat16* __restrict__ o,
                             int Cout, int Cin, int KK, int CoutPad) {
    int total = KK * CoutPad * Cin;
    int idx = blockIdx.x * blockDim.x + threadIdx.x;
    if (idx >= total) return;
    int cin = idx % Cin; int t = idx / Cin; int co = t % CoutPad; int kk = t / CoutPad;
    float v = (co < Cout) ? w[((size_t)co * Cin + cin) * KK + kk] : 0.0f;
    o[idx] = __float2bfloat16(v);
}

// ---------------- conv1: 3->96 @32x32, fp32 compute, LDS weights ----------------
__global__ __launch_bounds__(256) void conv1_kernel(
    const float* __restrict__ in,        // [B][34][34][4] f32 (ch3 = 0)
    const float* __restrict__ w,         // OIHW [96][3][3][3]
    const float* __restrict__ bias,      // [96]
    __hip_bfloat16* __restrict__ out) {  // [B][34][34][96]
    __shared__ float ws[96 * 27];
    __shared__ float bs[96];
    for (int i = threadIdx.x; i < 96 * 27; i += 256) ws[i] = w[i];
    for (int i = threadIdx.x; i < 96; i += 256) bs[i] = bias[i];
    __syncthreads();
    int idx = blockIdx.x * 256 + threadIdx.x;     // pixel id, exactly 131072
    int b = idx >> 10; int r = idx & 1023; int oh = r >> 5; int ow = r & 31;
    const float* ib = in + ((size_t)(b * 34 + oh) * 34 + ow) * 4;  // patch top-left
    float patch[9][3];
#pragma unroll
    for (int ph = 0; ph < 3; ++ph)
#pragma unroll
        for (int pw = 0; pw < 3; ++pw) {
            float4 q = *(const float4*)(ib + ((size_t)ph * 34 + pw) * 4);
            patch[ph * 3 + pw][0] = q.x; patch[ph * 3 + pw][1] = q.y; patch[ph * 3 + pw][2] = q.z;
        }
    __hip_bfloat16* ob = out + ((size_t)(b * 34 + oh + 1) * 34 + ow + 1) * 96;
    for (int co = 0; co < 96; ++co) {
        float acc = bs[co];
        const float* wc = &ws[co * 27];
#pragma unroll
        for (int ci = 0; ci < 3; ++ci)
#pragma unroll
            for (int pos = 0; pos < 9; ++pos)
                acc = fmaf(patch[pos][ci], wc[ci * 9 + pos], acc);
        ob[co] = __float2bfloat16(fmaxf(acc, 0.0f));
    }
}

// ---------------- MFMA implicit-GEMM conv (3x3 R=1 or 1x1 R=0), bias+relu+bf16 out ------
template <int CIN, int COUT, int HIN, int WIN, int STRIDE, int R>
__global__ __launch_bounds__(256) void mfma_conv(
    const __hip_bfloat16* __restrict__ in,   // [B][HIN+2][WIN+2][CIN]
    const __hip_bfloat16* __restrict__ wt,   // [(2R+1)^2][COUT][CIN] bf16
    const float* __restrict__ bias,          // [COUT]
    __hip_bfloat16* __restrict__ out) {      // [B][HOUT+2][WOUT+2][COUT]
    constexpr int HOUT = HIN / STRIDE, WOUT = WIN / STRIDE;
    constexpr int Hp = HIN + 2, Wp = WIN + 2;
    constexpr int Hpo = HOUT + 2, Wpo = WOUT + 2;
    constexpr int NT = COUT / 16;
    constexpr int KS = CIN / 32;
    constexpr int D = 2 * R + 1;
    constexpr int NPOS = D * D;
    constexpr int MT = 2;

    int wid = threadIdx.x >> 6;
    int lane = threadIdx.x & 63;
    int wave = blockIdx.x * 4 + wid;
    int m0 = wave * (16 * MT);
    int col = lane & 15;
    int kgrp = lane >> 4;

    const __hip_bfloat16* abase[MT];
#pragma unroll
    for (int mt = 0; mt < MT; ++mt) {
        int m = m0 + mt * 16 + col;                 // A row
        int b = m / (HOUT * WOUT);
        int r = m % (HOUT * WOUT);
        int oh = r / WOUT, ow = r % WOUT;
        int ih = oh * STRIDE + 1, iw = ow * STRIDE + 1;
        abase[mt] = in + ((size_t)(b * Hp + ih) * Wp + iw - (R * Wp + R)) * CIN + kgrp * 8;
    }

    f32x4 acc[MT][NT] = {};
    for (int pos = 0; pos < NPOS; ++pos) {
        int dh = pos / D, dw = pos % D;
        int aoff = (dh * Wp + dw) * CIN;
        const __hip_bfloat16* wpos = wt + (size_t)pos * COUT * CIN + kgrp * 8;
#pragma unroll
        for (int kk = 0; kk < KS; ++kk) {
            short8 a[MT];
#pragma unroll
            for (int mt = 0; mt < MT; ++mt)
                a[mt] = *reinterpret_cast<const short8*>(abase[mt] + aoff + kk * 32);
#pragma unroll
            for (int nt = 0; nt < NT; ++nt) {
                short8 bf = *reinterpret_cast<const short8*>(wpos + (size_t)(nt * 16 + col) * CIN + kk * 32);
#pragma unroll
                for (int mt = 0; mt < MT; ++mt)
                    acc[mt][nt] = __builtin_amdgcn_mfma_f32_16x16x32_bf16(a[mt], bf, acc[mt][nt], 0, 0, 0);
            }
        }
    }
    // epilogue: bias + relu + bf16 store into padded NHWC
#pragma unroll
    for (int mt = 0; mt < MT; ++mt) {
#pragma unroll
        for (int nt = 0; nt < NT; ++nt) {
            int cout = nt * 16 + col;
            float bv = bias[cout];
#pragma unroll
            for (int rg = 0; rg < 4; ++rg) {
                int m = m0 + mt * 16 + kgrp * 4 + rg;   // C/D row
                int b = m / (HOUT * WOUT);
                int r = m % (HOUT * WOUT);
                int oh = r / WOUT, ow = r % WOUT;
                float v = fmaxf(acc[mt][nt][rg] + bv, 0.0f);
                out[((size_t)(b * Hpo + oh + 1) * Wpo + ow + 1) * COUT + cout] = __float2bfloat16(v);
            }
        }
    }
}

// ---------------- conv9: 1x1 192->10 (padded to 16), relu, fp32 NCHW out [B][10][8][8] ---
__global__ __launch_bounds__(256) void conv9_kernel(
    const __hip_bfloat16* __restrict__ in,  // [B][10][10][192]
    const __hip_bfloat16* __restrict__ wt,  // [16][192] bf16 (rows 10..15 zero)
    const float* __restrict__ bias,         // [10]
    float* __restrict__ out) {              // [B][640]
    int wid = threadIdx.x >> 6;
    int lane = threadIdx.x & 63;
    int wave = blockIdx.x * 4 + wid;
    int m0 = wave * 32;
    int col = lane & 15;
    int kgrp = lane >> 4;
    const __hip_bfloat16* abase[2];
#pragma unroll
    for (int mt = 0; mt < 2; ++mt) {
        int m = m0 + mt * 16 + col;
        int b = m >> 6; int r = m & 63; int oh = r >> 3; int ow = r & 7;
        abase[mt] = in + ((size_t)(b * 10 + oh + 1) * 10 + ow + 1) * 192 + kgrp * 8;
    }
    f32x4 acc[2] = {};
    const __hip_bfloat16* wb = wt + (size_t)col * 192 + kgrp * 8;
#pragma unroll
    for (int kk = 0; kk < 6; ++kk) {
        short8 bf = *reinterpret_cast<const short8*>(wb + kk * 32);
#pragma unroll
        for (int mt = 0; mt < 2; ++mt) {
            short8 a = *reinterpret_cast<const short8*>(abase[mt] + kk * 32);
            acc[mt] = __builtin_amdgcn_mfma_f32_16x16x32_bf16(a, bf, acc[mt], 0, 0, 0);
        }
    }
    if (col < 10) {
        float bv = bias[col];
#pragma unroll
        for (int mt = 0; mt < 2; ++mt)
#pragma unroll
            for (int rg = 0; rg < 4; ++rg) {
                int m = m0 + mt * 16 + kgrp * 4 + rg;
                int b = m >> 6; int r = m & 63;
                out[(size_t)b * 640 + col * 64 + r] = fmaxf(acc[mt][rg] + bv, 0.0f);
            }
    }
}

// ---------------- fully-connected (fp32) ----------------
__global__ void fc_kernel(const float* __restrict__ in, const float* __restrict__ wt,
                          const float* __restrict__ bias, float* __restrict__ out,
                          int IN, int OUT, int relu) {
    int idx = blockIdx.x * blockDim.x + threadIdx.x;
    if (idx >= BATCH * OUT) return;
    int o = idx % OUT, b = idx / OUT;
    const float* inb = in + (size_t)b * IN;
    const float* wo = wt + (size_t)o * IN;
    float acc = bias[o];
    for (int i = 0; i < IN; ++i) acc = fmaf(inb[i], wo[i], acc);
    out[idx] = relu ? fmaxf(acc, 0.0f) : acc;
}

// ---------------- final encode ----------------
__global__ void encode_kernel(const float* __restrict__ logits, const int* __restrict__ p,
                              const float* __restrict__ s, float* __restrict__ out) {
    int idx = blockIdx.x * blockDim.x + threadIdx.x;
    if (idx >= BATCH * 11) return;
    int i = idx % 11, b = idx / 11;
    int pi = p[i];
    float v = (pi == 10) ? 1.0f : logits[(size_t)b * 10 + pi];
    out[idx] = s[i] * v;
}

extern "C" void kernel_launch(void* const* d_in, const int* in_sizes, int n_in,
                              void* d_out, int out_size, void* d_ws, size_t ws_size,
                              hipStream_t stream) {
    const int*   p0  = (const int*)  d_in[0];
    const float* s0  = (const float*)d_in[1];
    const int*   p11 = (const int*)  d_in[26];
    const float* s11 = (const float*)d_in[27];
    const float* w1 = (const float*)d_in[28]; const float* b1 = (const float*)d_in[29];
    const float* w2 = (const float*)d_in[30]; const float* b2 = (const float*)d_in[31];
    const float* w3 = (const float*)d_in[32]; const float* b3 = (const float*)d_in[33];
    const float* w4 = (const float*)d_in[34]; const float* b4 = (const float*)d_in[35];
    const float* w5 = (const float*)d_in[36]; const float* b5 = (const float*)d_in[37];
    const float* w6 = (const float*)d_in[38]; const float* b6 = (const float*)d_in[39];
    const float* w7 = (const float*)d_in[40]; const float* b7 = (const float*)d_in[41];
    const float* w8 = (const float*)d_in[42]; const float* b8 = (const float*)d_in[43];
    const float* w9 = (const float*)d_in[44]; const float* b9 = (const float*)d_in[45];
    const float* fw1 = (const float*)d_in[46]; const float* fb1 = (const float*)d_in[47];
    const float* fw2 = (const float*)d_in[48]; const float* fb2 = (const float*)d_in[49];
    const float* A0 = (const float*)d_in[50];
    float* out = (float*)d_out;

    // ---- workspace carve-up (256B aligned) ----
    size_t off = 0;
    auto alloc = [&](size_t bytes) {
        void* p = (char*)d_ws + off;
        off += (bytes + 255) & ~(size_t)255;
        return p;
    };
    float*          dec  = (float*)alloc((size_t)BATCH * 34 * 34 * 4 * 4);           // 2.37 MB
    __hip_bfloat16* bufA = (__hip_bfloat16*)alloc((size_t)BATCH * 34 * 34 * 96 * 2); // 28.4 MB
    __hip_bfloat16* bufB = (__hip_bfloat16*)alloc((size_t)BATCH * 34 * 34 * 96 * 2); // 28.4 MB
    __hip_bfloat16* wt2 = (__hip_bfloat16*)alloc((size_t)9 * 96 * 96 * 2);
    __hip_bfloat16* wt3 = (__hip_bfloat16*)alloc((size_t)9 * 96 * 96 * 2);
    __hip_bfloat16* wt4 = (__hip_bfloat16*)alloc((size_t)9 * 192 * 96 * 2);
    __hip_bfloat16* wt5 = (__hip_bfloat16*)alloc((size_t)9 * 192 * 192 * 2);
    __hip_bfloat16* wt6 = (__hip_bfloat16*)alloc((size_t)9 * 192 * 192 * 2);
    __hip_bfloat16* wt7 = (__hip_bfloat16*)alloc((size_t)9 * 192 * 192 * 2);
    __hip_bfloat16* wt8 = (__hip_bfloat16*)alloc((size_t)1 * 192 * 192 * 2);
    __hip_bfloat16* wt9 = (__hip_bfloat16*)alloc((size_t)16 * 192 * 2);
    float* act9 = (float*)alloc((size_t)BATCH * 640 * 4);
    float* fco1 = (float*)alloc((size_t)BATCH * 100 * 4);
    float* fco2 = (float*)alloc((size_t)BATCH * 10 * 4);

    const int TPB = 256;

    // decode input (zero-fill padded buffer first: halo + ch3)
    int decN = BATCH * 34 * 34 * 4;
    fill0_f32<<<CDIV(decN, TPB), TPB, 0, stream>>>(dec, decN);
    decode_kernel<<<CDIV(BATCH * 3073, TPB), TPB, 0, stream>>>(A0, p0, s0, dec);

    // weight transforms (every launch; deterministic)
    wt_transform<<<CDIV(9 * 96 * 96, TPB), TPB, 0, stream>>>(w2, wt2, 96, 96, 9, 96);
    wt_transform<<<CDIV(9 * 96 * 96, TPB), TPB, 0, stream>>>(w3, wt3, 96, 96, 9, 96);
    wt_transform<<<CDIV(9 * 192 * 96, TPB), TPB, 0, stream>>>(w4, wt4, 192, 96, 9, 192);
    wt_transform<<<CDIV(9 * 192 * 192, TPB), TPB, 0, stream>>>(w5, wt5, 192, 192, 9, 192);
    wt_transform<<<CDIV(9 * 192 * 192, TPB), TPB, 0, stream>>>(w6, wt6, 192, 192, 9, 192);
    wt_transform<<<CDIV(9 * 192 * 192, TPB), TPB, 0, stream>>>(w7, wt7, 192, 192, 9, 192);
    wt_transform<<<CDIV(1 * 192 * 192, TPB), TPB, 0, stream>>>(w8, wt8, 192, 192, 1, 192);
    wt_transform<<<CDIV(1 * 16 * 192, TPB), TPB, 0, stream>>>(w9, wt9, 10, 192, 1, 16);

    // conv1: dec -> bufA [34,34,96]
    halo_zero<<<CDIV(BATCH * (2 * 34 + 2 * 32) * 96, TPB), TPB, 0, stream>>>(bufA, 34, 34, 96);
    conv1_kernel<<<512, 256, 0, stream>>>(dec, w1, b1, bufA);
    // conv2: bufA -> bufB [34,34,96]   M=131072
    halo_zero<<<CDIV(BATCH * (2 * 34 + 2 * 32) * 96, TPB), TPB, 0, stream>>>(bufB, 34, 34, 96);
    mfma_conv<96, 96, 32, 32, 1, 1><<<1024, 256, 0, stream>>>(bufA, wt2, b2, bufB);
    // conv3 (s2): bufB -> bufA [18,18,96]  M=32768
    halo_zero<<<CDIV(BATCH * (2 * 18 + 2 * 16) * 96, TPB), TPB, 0, stream>>>(bufA, 18, 18, 96);
    mfma_conv<96, 96, 32, 32, 2, 1><<<256, 256, 0, stream>>>(bufB, wt3, b3, bufA);
    // conv4: bufA -> bufB [18,18,192]  M=32768
    halo_zero<<<CDIV(BATCH * (2 * 18 + 2 * 16) * 192, TPB), TPB, 0, stream>>>(bufB, 18, 18, 192);
    mfma_conv<96, 192, 16, 16, 1, 1><<<256, 256, 0, stream>>>(bufA, wt4, b4, bufB);
    // conv5: bufB -> bufA [18,18,192]  M=32768
    halo_zero<<<CDIV(BATCH * (2 * 18 + 2 * 16) * 192, TPB), TPB, 0, stream>>>(bufA, 18, 18, 192);
    mfma_conv<192, 192, 16, 16, 1, 1><<<256, 256, 0, stream>>>(bufB, wt5, b5, bufA);
    // conv6 (s2): bufA -> bufB [10,10,192]  M=8192
    halo_zero<<<CDIV(BATCH * (2 * 10 + 2 * 8) * 192, TPB), TPB, 0, stream>>>(bufB, 10, 10, 192);
    mfma_conv<192, 192, 16, 16, 2, 1><<<64, 256, 0, stream>>>(bufA, wt6, b6, bufB);
    // conv7: bufB -> bufA [10,10,192]  M=8192
    halo_zero<<<CDIV(BATCH * (2 * 10 + 2 * 8) * 192, TPB), TPB, 0, stream>>>(bufA, 10, 10, 192);
    mfma_conv<192, 192, 8, 8, 1, 1><<<64, 256, 0, stream>>>(bufB, wt7, b7, bufA);
    // conv8 (1x1): bufA -> bufB [10,10,192]  (halo of bufB still zero from conv6 prep)
    mfma_conv<192, 192, 8, 8, 1, 0><<<64, 256, 0, stream>>>(bufA, wt8, b8, bufB);
    // conv9 (1x1, 192->10): bufB -> act9 fp32 NCHW flat
    conv9_kernel<<<64, 256, 0, stream>>>(bufB, wt9, b9, act9);

    // fc1 / fc2 / encode (fp32)
    fc_kernel<<<CDIV(BATCH * 100, TPB), TPB, 0, stream>>>(act9, fw1, fb1, fco1, 640, 100, 1);
    fc_kernel<<<CDIV(BATCH * 10, TPB), TPB, 0, stream>>>(fco1, fw2, fb2, fco2, 100, 10, 0);
    encode_kernel<<<CDIV(BATCH * 11, TPB), TPB, 0, stream>>>(fco2, p11, s11, out);
}

// Round 3
// 433.726 us; speedup vs baseline: 29.2430x; 1.7992x over previous
//
#include <hip/hip_runtime.h>
#include <hip/hip_bf16.h>

#define BATCH 128
#define CDIV(a, b) (((a) + (b) - 1) / (b))

typedef __attribute__((ext_vector_type(8))) short short8;
typedef __attribute__((ext_vector_type(4))) float f32x4;

// ---------------- zero fill (f32) ----------------
__global__ void fill0_f32(float* __restrict__ p, int n) {
    int i = blockIdx.x * blockDim.x + threadIdx.x;
    if (i < n) p[i] = 0.0f;
}

// ---------------- decode: scatter A0 -> padded NHWC f32 [B][34][34][4] ----------------
__global__ void decode_kernel(const float* __restrict__ y, const int* __restrict__ p,
                              const float* __restrict__ s, float* __restrict__ x) {
    const int n = 3073;
    int idx = blockIdx.x * blockDim.x + threadIdx.x;
    if (idx >= BATCH * n) return;
    int i = idx % n, b = idx / n;
    int pi = p[i];
    if (pi >= 3072) return;
    float v = y[(size_t)b * n + i] / s[i];
    int c = pi >> 10; int r = pi & 1023; int h = r >> 5; int w = r & 31;
    x[((size_t)(b * 34 + h + 1) * 34 + (w + 1)) * 4 + c] = v;
}

// ---------------- fused halo zero (up to 4 padded bf16 NHWC buffers) ----------------
struct HaloDesc { __hip_bfloat16* p; int Hp, Wp, C; };
struct Halo4 { HaloDesc d[4]; int cum[5]; int n; };

__global__ void halo_zero_multi(Halo4 h) {
    int idx = blockIdx.x * 256 + threadIdx.x;
    if (idx >= h.cum[h.n]) return;
    int seg = 0;
    while (idx >= h.cum[seg + 1]) ++seg;
    int local = idx - h.cum[seg];
    HaloDesc d = h.d[seg];
    int perB = (2 * d.Wp + 2 * (d.Hp - 2)) * d.C / 8;   // 16B chunks per batch
    int b = local / perB;
    int r = (local % perB) * 8;                          // elem within this batch's halo
    int WpC = d.Wp * d.C;
    long addr;
    if (r < WpC) {
        addr = (long)(b * d.Hp) * WpC + r;               // top row
    } else if (r < 2 * WpC) {
        addr = (long)(b * d.Hp + d.Hp - 1) * WpC + (r - WpC);  // bottom row
    } else {
        int r3 = r - 2 * WpC;
        int sideN = (d.Hp - 2) * d.C;
        int side = r3 / sideN;                           // 0=left col, 1=right col
        int r4 = r3 % sideN;
        int row = 1 + r4 / d.C, c = r4 % d.C;
        addr = ((long)(b * d.Hp + row) * d.Wp + (side ? d.Wp - 1 : 0)) * d.C + c;
    }
    *(uint4*)((char*)d.p + addr * 2) = uint4{0, 0, 0, 0};
}

// ---------------- fused weight transform: OIHW f32 -> [KK][CoutPad][Cin] bf16 ----------
struct WtSeg { const float* src; __hip_bfloat16* dst; int Cout, Cin, KK, CoutPad; };
struct Wt8 { WtSeg s[8]; int cum[9]; };

__global__ void wt_transform_multi(Wt8 w) {
    int idx = blockIdx.x * 256 + threadIdx.x;
    if (idx >= w.cum[8]) return;
    int seg = 0;
    while (idx >= w.cum[seg + 1]) ++seg;
    int local = idx - w.cum[seg];
    WtSeg sg = w.s[seg];
    int cin = local % sg.Cin; int t = local / sg.Cin;
    int co = t % sg.CoutPad; int kk = t / sg.CoutPad;
    float v = (co < sg.Cout) ? sg.src[((size_t)co * sg.Cin + cin) * sg.KK + kk] : 0.0f;
    sg.dst[local] = __float2bfloat16(v);
}

// ---------------- conv1: 3->96 @32x32, fp32, 4 threads/pixel, packed stores ------------
__global__ __launch_bounds__(256) void conv1_kernel(
    const float* __restrict__ in,        // [B][34][34][4] f32 (ch3 = 0)
    const float* __restrict__ w,         // OIHW [96][3][3][3]
    const float* __restrict__ bias,      // [96]
    __hip_bfloat16* __restrict__ out) {  // [B][34][34][96]
    __shared__ float ws[96 * 27];
    __shared__ float bs[96];
    for (int i = threadIdx.x; i < 96 * 27; i += 256) ws[i] = w[i];
    if (threadIdx.x < 96) bs[threadIdx.x] = bias[threadIdx.x];
    __syncthreads();
    int idx = blockIdx.x * 256 + threadIdx.x;   // over 131072*4
    int q = idx & 3; int pix = idx >> 2;
    int b = pix >> 10, r = pix & 1023, oh = r >> 5, ow = r & 31;
    const float* ib = in + ((size_t)(b * 34 + oh) * 34 + ow) * 4;
    float patch[9][3];
#pragma unroll
    for (int ph = 0; ph < 3; ++ph)
#pragma unroll
        for (int pw = 0; pw < 3; ++pw) {
            float4 v = *(const float4*)(ib + ((size_t)ph * 34 + pw) * 4);
            patch[ph * 3 + pw][0] = v.x; patch[ph * 3 + pw][1] = v.y; patch[ph * 3 + pw][2] = v.z;
        }
    const int c0 = q * 24;
    float acc[24];
#pragma unroll
    for (int j = 0; j < 24; ++j) acc[j] = bs[c0 + j];
    for (int j = 0; j < 24; ++j) {
        const float* wc = &ws[(c0 + j) * 27];
#pragma unroll
        for (int ci = 0; ci < 3; ++ci)
#pragma unroll
            for (int pos = 0; pos < 9; ++pos)
                acc[j] = fmaf(patch[pos][ci], wc[ci * 9 + pos], acc[j]);
    }
    __hip_bfloat16* ob = out + ((size_t)(b * 34 + oh + 1) * 34 + ow + 1) * 96 + c0;
#pragma unroll
    for (int g = 0; g < 3; ++g) {
        union { uint4 u; unsigned short s[8]; } pk;
#pragma unroll
        for (int e = 0; e < 8; ++e) {
            __hip_bfloat16 hv = __float2bfloat16(fmaxf(acc[g * 8 + e], 0.0f));
            pk.s[e] = *(unsigned short*)&hv;
        }
        *(uint4*)(ob + g * 8) = pk.u;
    }
}

// ---------------- MFMA implicit-GEMM conv, tiled M x (NTW*16) per wave -----------------
template <int CIN, int COUT, int HIN, int WIN, int STRIDE, int R, int MT, int NTW>
__global__ __launch_bounds__(256, 3) void mfma_conv(
    const __hip_bfloat16* __restrict__ in,   // [B][HIN+2][WIN+2][CIN]
    const __hip_bfloat16* __restrict__ wt,   // [(2R+1)^2][COUT][CIN] bf16
    const float* __restrict__ bias,          // [COUT]
    __hip_bfloat16* __restrict__ out) {      // [B][HOUT+2][WOUT+2][COUT]
    constexpr int HOUT = HIN / STRIDE, WOUT = WIN / STRIDE;
    constexpr int Hp = HIN + 2, Wp = WIN + 2;
    constexpr int Hpo = HOUT + 2, Wpo = WOUT + 2;
    constexpr int KS = CIN / 32;
    constexpr int D = 2 * R + 1;
    constexpr int NPOS = D * D;
    constexpr int NB = COUT / (16 * NTW);

    int wid = threadIdx.x >> 6;
    int lane = threadIdx.x & 63;
    int wave = blockIdx.x * 4 + wid;
    int mtile = wave / NB;
    int ntile = wave % NB;
    int m0 = mtile * (16 * MT);
    int n0 = ntile * (16 * NTW);
    int col = lane & 15;
    int kgrp = lane >> 4;

    const __hip_bfloat16* abase[MT];
#pragma unroll
    for (int mt = 0; mt < MT; ++mt) {
        int m = m0 + mt * 16 + col;
        int b = m / (HOUT * WOUT);
        int r = m % (HOUT * WOUT);
        int oh = r / WOUT, ow = r % WOUT;
        int ih = oh * STRIDE + 1, iw = ow * STRIDE + 1;
        abase[mt] = in + ((size_t)(b * Hp + ih) * Wp + iw - (R * Wp + R)) * CIN + kgrp * 8;
    }
    const __hip_bfloat16* bbase[NTW];
#pragma unroll
    for (int nt = 0; nt < NTW; ++nt)
        bbase[nt] = wt + (size_t)(n0 + nt * 16 + col) * CIN + kgrp * 8;

    f32x4 acc[MT][NTW] = {};
#pragma unroll
    for (int pos = 0; pos < NPOS; ++pos) {
        int dh = pos / D, dw = pos % D;
        int aoff = (dh * Wp + dw) * CIN;
        size_t woff = (size_t)pos * COUT * CIN;
#pragma unroll
        for (int kk = 0; kk < KS; ++kk) {
            short8 a[MT];
#pragma unroll
            for (int mt = 0; mt < MT; ++mt)
                a[mt] = *reinterpret_cast<const short8*>(abase[mt] + aoff + kk * 32);
#pragma unroll
            for (int nt = 0; nt < NTW; ++nt) {
                short8 bf = *reinterpret_cast<const short8*>(bbase[nt] + woff + kk * 32);
#pragma unroll
                for (int mt = 0; mt < MT; ++mt)
                    acc[mt][nt] = __builtin_amdgcn_mfma_f32_16x16x32_bf16(a[mt], bf, acc[mt][nt], 0, 0, 0);
            }
        }
    }
    // epilogue: bias + relu + bf16 store into padded NHWC
#pragma unroll
    for (int mt = 0; mt < MT; ++mt) {
#pragma unroll
        for (int nt = 0; nt < NTW; ++nt) {
            int cout = n0 + nt * 16 + col;
            float bv = bias[cout];
#pragma unroll
            for (int rg = 0; rg < 4; ++rg) {
                int m = m0 + mt * 16 + kgrp * 4 + rg;
                int b = m / (HOUT * WOUT);
                int r = m % (HOUT * WOUT);
                int oh = r / WOUT, ow = r % WOUT;
                float v = fmaxf(acc[mt][nt][rg] + bv, 0.0f);
                out[((size_t)(b * Hpo + oh + 1) * Wpo + ow + 1) * COUT + cout] = __float2bfloat16(v);
            }
        }
    }
}

// ---------------- conv9: 1x1 192->10 (pad16), relu, fp32 NCHW-flat out [B][640] --------
__global__ __launch_bounds__(256) void conv9_kernel(
    const __hip_bfloat16* __restrict__ in,  // [B][10][10][192]
    const __hip_bfloat16* __restrict__ wt,  // [16][192] bf16 (rows 10..15 zero)
    const float* __restrict__ bias,         // [10]
    float* __restrict__ out) {              // [B][640]
    int wid = threadIdx.x >> 6;
    int lane = threadIdx.x & 63;
    int wave = blockIdx.x * 4 + wid;
    int m0 = wave * 16;
    int col = lane & 15;
    int kgrp = lane >> 4;
    int m = m0 + col;
    int b = m >> 6; int r = m & 63; int oh = r >> 3; int ow = r & 7;
    const __hip_bfloat16* abase = in + ((size_t)(b * 10 + oh + 1) * 10 + ow + 1) * 192 + kgrp * 8;
    const __hip_bfloat16* wb = wt + (size_t)col * 192 + kgrp * 8;
    f32x4 acc = {};
#pragma unroll
    for (int kk = 0; kk < 6; ++kk) {
        short8 bf = *reinterpret_cast<const short8*>(wb + kk * 32);
        short8 a = *reinterpret_cast<const short8*>(abase + kk * 32);
        acc = __builtin_amdgcn_mfma_f32_16x16x32_bf16(a, bf, acc, 0, 0, 0);
    }
    if (col < 10) {
        float bv = bias[col];
#pragma unroll
        for (int rg = 0; rg < 4; ++rg) {
            int m2 = m0 + kgrp * 4 + rg;
            int b2 = m2 >> 6; int r2 = m2 & 63;
            out[(size_t)b2 * 640 + col * 64 + r2] = fmaxf(acc[rg] + bv, 0.0f);
        }
    }
}

// ---------------- fused head: fc1(640->100)+relu, fc2(100->10), encode -----------------
__global__ __launch_bounds__(128) void head_kernel(
    const float* __restrict__ act9, const float* __restrict__ fw1, const float* __restrict__ fb1,
    const float* __restrict__ fw2, const float* __restrict__ fb2,
    const int* __restrict__ p11, const float* __restrict__ s11, float* __restrict__ out) {
    __shared__ float x[640];
    __shared__ float h[100];
    __shared__ float o[10];
    int b = blockIdx.x, t = threadIdx.x;
    for (int i = t; i < 160; i += 128)
        ((float4*)x)[i] = ((const float4*)(act9 + (size_t)b * 640))[i];
    __syncthreads();
    if (t < 100) {
        float acc = fb1[t];
        const float4* wr = (const float4*)(fw1 + (size_t)t * 640);
        const float4* xv = (const float4*)x;
#pragma unroll 4
        for (int i = 0; i < 160; ++i) {
            float4 wv = wr[i], qv = xv[i];
            acc = fmaf(wv.x, qv.x, acc); acc = fmaf(wv.y, qv.y, acc);
            acc = fmaf(wv.z, qv.z, acc); acc = fmaf(wv.w, qv.w, acc);
        }
        h[t] = fmaxf(acc, 0.0f);
    }
    __syncthreads();
    if (t < 10) {
        float acc = fb2[t];
        for (int i = 0; i < 100; ++i) acc = fmaf(h[i], fw2[t * 100 + i], acc);
        o[t] = acc;
    }
    __syncthreads();
    if (t < 11) {
        int pi = p11[t];
        out[(size_t)b * 11 + t] = s11[t] * (pi == 10 ? 1.0f : o[pi]);
    }
}

extern "C" void kernel_launch(void* const* d_in, const int* in_sizes, int n_in,
                              void* d_out, int out_size, void* d_ws, size_t ws_size,
                              hipStream_t stream) {
    const int*   p0  = (const int*)  d_in[0];
    const float* s0  = (const float*)d_in[1];
    const int*   p11 = (const int*)  d_in[26];
    const float* s11 = (const float*)d_in[27];
    const float* w1 = (const float*)d_in[28]; const float* b1 = (const float*)d_in[29];
    const float* w2 = (const float*)d_in[30]; const float* b2 = (const float*)d_in[31];
    const float* w3 = (const float*)d_in[32]; const float* b3 = (const float*)d_in[33];
    const float* w4 = (const float*)d_in[34]; const float* b4 = (const float*)d_in[35];
    const float* w5 = (const float*)d_in[36]; const float* b5 = (const float*)d_in[37];
    const float* w6 = (const float*)d_in[38]; const float* b6 = (const float*)d_in[39];
    const float* w7 = (const float*)d_in[40]; const float* b7 = (const float*)d_in[41];
    const float* w8 = (const float*)d_in[42]; const float* b8 = (const float*)d_in[43];
    const float* w9 = (const float*)d_in[44]; const float* b9 = (const float*)d_in[45];
    const float* fw1 = (const float*)d_in[46]; const float* fb1 = (const float*)d_in[47];
    const float* fw2 = (const float*)d_in[48]; const float* fb2 = (const float*)d_in[49];
    const float* A0 = (const float*)d_in[50];
    float* out = (float*)d_out;

    // ---- workspace carve-up (256B aligned) ----
    size_t off = 0;
    auto alloc = [&](size_t bytes) {
        void* p = (char*)d_ws + off;
        off += (bytes + 255) & ~(size_t)255;
        return p;
    };
    const size_t SZ_3434_96  = (size_t)BATCH * 34 * 34 * 96 * 2;   // 28.4 MB
    const size_t SZ_1818_96  = (size_t)BATCH * 18 * 18 * 96 * 2;   // 8.0 MB
    const size_t SZ_1818_192 = (size_t)BATCH * 18 * 18 * 192 * 2;  // 15.9 MB

    float* dec = (float*)alloc((size_t)BATCH * 34 * 34 * 4 * 4);
    __hip_bfloat16* regA = (__hip_bfloat16*)alloc(SZ_3434_96);   // act1 [34,34,96]; act5 [18,18,192]
    __hip_bfloat16* regB = (__hip_bfloat16*)alloc(SZ_3434_96);   // act2 [34,34,96]; act8 [10,10,192]
    __hip_bfloat16* regC = (__hip_bfloat16*)alloc(SZ_1818_96);   // act3 [18,18,96]; act6 [10,10,192]
    __hip_bfloat16* regD = (__hip_bfloat16*)alloc(SZ_1818_192);  // act4 [18,18,192]; act7 [10,10,192]
    __hip_bfloat16* wt2 = (__hip_bfloat16*)alloc((size_t)9 * 96 * 96 * 2);
    __hip_bfloat16* wt3 = (__hip_bfloat16*)alloc((size_t)9 * 96 * 96 * 2);
    __hip_bfloat16* wt4 = (__hip_bfloat16*)alloc((size_t)9 * 192 * 96 * 2);
    __hip_bfloat16* wt5 = (__hip_bfloat16*)alloc((size_t)9 * 192 * 192 * 2);
    __hip_bfloat16* wt6 = (__hip_bfloat16*)alloc((size_t)9 * 192 * 192 * 2);
    __hip_bfloat16* wt7 = (__hip_bfloat16*)alloc((size_t)9 * 192 * 192 * 2);
    __hip_bfloat16* wt8 = (__hip_bfloat16*)alloc((size_t)1 * 192 * 192 * 2);
    __hip_bfloat16* wt9 = (__hip_bfloat16*)alloc((size_t)16 * 192 * 2);
    float* act9 = (float*)alloc((size_t)BATCH * 640 * 4);

    const int TPB = 256;

    // decode input
    int decN = BATCH * 34 * 34 * 4;
    fill0_f32<<<CDIV(decN, TPB), TPB, 0, stream>>>(dec, decN);
    decode_kernel<<<CDIV(BATCH * 3073, TPB), TPB, 0, stream>>>(A0, p0, s0, dec);

    // fused weight transform
    Wt8 wts;
    wts.s[0] = {w2, wt2, 96, 96, 9, 96};
    wts.s[1] = {w3, wt3, 96, 96, 9, 96};
    wts.s[2] = {w4, wt4, 192, 96, 9, 192};
    wts.s[3] = {w5, wt5, 192, 192, 9, 192};
    wts.s[4] = {w6, wt6, 192, 192, 9, 192};
    wts.s[5] = {w7, wt7, 192, 192, 9, 192};
    wts.s[6] = {w8, wt8, 192, 192, 1, 192};
    wts.s[7] = {w9, wt9, 10, 192, 1, 16};
    wts.cum[0] = 0;
    for (int i = 0; i < 8; ++i)
        wts.cum[i + 1] = wts.cum[i] + wts.s[i].KK * wts.s[i].CoutPad * wts.s[i].Cin;
    wt_transform_multi<<<CDIV(wts.cum[8], TPB), TPB, 0, stream>>>(wts);

    // fused halo zero: act1, act2, act3, act4
    auto chunks = [](int Hp, int Wp, int C) { return BATCH * (2 * Wp + 2 * (Hp - 2)) * C / 8; };
    Halo4 h0;
    h0.d[0] = {regA, 34, 34, 96};
    h0.d[1] = {regB, 34, 34, 96};
    h0.d[2] = {regC, 18, 18, 96};
    h0.d[3] = {regD, 18, 18, 192};
    h0.n = 4; h0.cum[0] = 0;
    for (int i = 0; i < 4; ++i)
        h0.cum[i + 1] = h0.cum[i] + chunks(h0.d[i].Hp, h0.d[i].Wp, h0.d[i].C);
    halo_zero_multi<<<CDIV(h0.cum[4], TPB), TPB, 0, stream>>>(h0);

    // conv1: dec -> act1 (regA)
    conv1_kernel<<<2048, 256, 0, stream>>>(dec, w1, b1, regA);
    // conv2: act1 -> act2 (regB)   M=131072, waves 8192
    mfma_conv<96, 96, 32, 32, 1, 1, 2, 3><<<2048, 256, 0, stream>>>(regA, wt2, b2, regB);
    // re-zero act5 halo (regA reused as [18,18,192])
    Halo4 h5; h5.d[0] = {regA, 18, 18, 192}; h5.n = 1;
    h5.cum[0] = 0; h5.cum[1] = chunks(18, 18, 192);
    halo_zero_multi<<<CDIV(h5.cum[1], TPB), TPB, 0, stream>>>(h5);
    // conv3 (s2): act2 -> act3 (regC)   M=32768, waves 2048
    mfma_conv<96, 96, 32, 32, 2, 1, 2, 3><<<512, 256, 0, stream>>>(regB, wt3, b3, regC);
    // conv4: act3 -> act4 (regD)   M=32768, waves 4096
    mfma_conv<96, 192, 16, 16, 1, 1, 2, 3><<<1024, 256, 0, stream>>>(regC, wt4, b4, regD);
    // re-zero act6 halo (regC reused as [10,10,192])
    Halo4 h6; h6.d[0] = {regC, 10, 10, 192}; h6.n = 1;
    h6.cum[0] = 0; h6.cum[1] = chunks(10, 10, 192);
    halo_zero_multi<<<CDIV(h6.cum[1], TPB), TPB, 0, stream>>>(h6);
    // conv5: act4 -> act5 (regA)   M=32768, waves 4096
    mfma_conv<192, 192, 16, 16, 1, 1, 2, 3><<<1024, 256, 0, stream>>>(regD, wt5, b5, regA);
    // conv6 (s2): act5 -> act6 (regC)   M=8192, waves 2048
    mfma_conv<192, 192, 16, 16, 2, 1, 1, 3><<<512, 256, 0, stream>>>(regA, wt6, b6, regC);
    // conv7: act6 -> act7 (regD)   M=8192, waves 2048
    mfma_conv<192, 192, 8, 8, 1, 1, 1, 3><<<512, 256, 0, stream>>>(regC, wt7, b7, regD);
    // conv8 (1x1): act7 -> act8 (regB)   M=8192, waves 2048
    mfma_conv<192, 192, 8, 8, 1, 0, 1, 3><<<512, 256, 0, stream>>>(regD, wt8, b8, regB);
    // conv9 (1x1 192->10): act8 -> act9 fp32
    conv9_kernel<<<128, 256, 0, stream>>>(regB, wt9, b9, act9);
    // fused fc1+fc2+encode
    head_kernel<<<BATCH, 128, 0, stream>>>(act9, fw1, fb1, fw2, fb2, p11, s11, out);
}